// Round 8
// baseline (788.521 us; speedup 1.0000x reference)
//
#include <hip/hip_runtime.h>

#define N_PIX 4096
#define N_CH 256
#define KSEL 16
#define WCAP 32  // per-wave padded slab size (E[cands/wave] ~ 18)

__device__ __forceinline__ unsigned f2key(float f) {
  unsigned u = __float_as_uint(f);
  return u ^ ((unsigned)((int)u >> 31) | 0x80000000u);
}
__device__ __forceinline__ float key2f(unsigned k) {
  unsigned u = (k & 0x80000000u) ? (k ^ 0x80000000u) : ~k;
  return __uint_as_float(u);
}
__device__ __forceinline__ unsigned umax2(unsigned a, unsigned b) { return a > b ? a : b; }

// feat [B, C, N] -> feat_t [B, N, C], 32x32 LDS tile transpose
__global__ void transpose_feat_kernel(const float* __restrict__ feat,
                                      float* __restrict__ feat_t) {
  __shared__ float tile[32][33];
  const int b = blockIdx.z;
  const int n0 = blockIdx.x * 32;
  const int c0 = blockIdx.y * 32;
  const int tx = threadIdx.x, ty = threadIdx.y;
  const float* src = feat + (size_t)b * N_CH * N_PIX;
  float* dst = feat_t + (size_t)b * N_PIX * N_CH;
#pragma unroll
  for (int j = 0; j < 32; j += 8)
    tile[ty + j][tx] = src[(size_t)(c0 + ty + j) * N_PIX + n0 + tx];
  __syncthreads();
#pragma unroll
  for (int j = 0; j < 32; j += 8)
    dst[(size_t)(n0 + ty + j) * N_CH + c0 + tx] = tile[tx][ty + j];
}

// Block = 256 threads per row (16 keys/thread), 4 rows sequential, prefetched.
//   per wave:  T1 = exact 16th-largest of its 64 thread-maxima (branchless
//              32-step ballot-radix; T1 <= v16(row) since >=16 of the wave's
//              elements are >= T1). Compact elems >= T1 into a PADDED 32-slot
//              slab (pads (key=0, idx=~0) lose every rank tie).
//   final:     128 threads rank the 128 padded candidates (value desc, idx
//              asc == jax.lax.top_k semantics) via fully-unrolled LDS
//              broadcast reads; winners rank<16. Row max falls out free.
// 2 barriers/row; no wave0-only serial stage; no runtime-bounded loops.
// __launch_bounds__(256,8): VGPR<=64 so all 8 blocks/CU are co-resident.
template <bool FT>
__global__ __launch_bounds__(256, 8) void topk_rank2_kernel(
    const float* __restrict__ aff, const float* __restrict__ feat,
    float* __restrict__ out) {
  __shared__ uint2 s_cand[4][WCAP];  // (key, idx), padded
  __shared__ uint2 s_wj[KSEL];       // (exp(v - vmax) bits, idx)

  const int tid = threadIdx.x;
  const int lane = tid & 63;
  const int w = tid >> 6;
  // chunked bijective XCD swizzle: rg-consecutive blocks share an XCD so the
  // blocks writing each 64B output line write-combine in one L2 (R6: 8.2MB).
  const int bid = blockIdx.x;
  const int rg = (bid & 7) * 256 + (bid >> 3);
  const int b = rg >> 10;
  const int i0 = (rg & 1023) * 4;
  const unsigned long long lt = (1ull << lane) - 1ull;

  const float* aff_rg = aff + (size_t)rg * 4 * N_PIX;
  float accs[4];

  // prefetch row 0
  float4 pv[4];
#pragma unroll
  for (int q = 0; q < 4; ++q) pv[q] = ((const float4*)aff_rg)[q * 256 + tid];

  for (int r = 0; r < 4; ++r) {
    unsigned key[16];
#pragma unroll
    for (int q = 0; q < 4; ++q) {
      key[q * 4 + 0] = f2key(pv[q].x);
      key[q * 4 + 1] = f2key(pv[q].y);
      key[q * 4 + 2] = f2key(pv[q].z);
      key[q * 4 + 3] = f2key(pv[q].w);
    }
    // issue next row's loads; they fly under this row's compute
    if (r < 3) {
      const float4* nxt = (const float4*)(aff_rg + (size_t)(r + 1) * N_PIX);
#pragma unroll
      for (int q = 0; q < 4; ++q) pv[q] = nxt[q * 256 + tid];
    }

    // thread max
    unsigned m = key[0];
#pragma unroll
    for (int e = 1; e < 16; ++e) m = umax2(m, key[e]);

    // ---- T1: exact 16th-largest of the wave's 64 maxima (branchless radix) ----
    unsigned p1 = 0, need1 = KSEL;
#pragma unroll
    for (int bit = 31; bit >= 0; --bit) {
      const unsigned want = (p1 << 1) | 1u;
      const unsigned cnt = (unsigned)__popcll(__ballot((m >> bit) == want));
      const bool take = cnt >= need1;
      p1 = want - (take ? 0u : 1u);
      need1 = take ? need1 : need1 - cnt;
    }
    const unsigned T1 = p1;

    // ---- pad slab, then ballot-rank compact elems >= T1 (same-wave order) ----
    if (lane < WCAP) s_cand[w][lane] = make_uint2(0u, 0xFFFFFFFFu);
    unsigned base = 0;
#pragma unroll
    for (int e = 0; e < 16; ++e) {
      const bool sel = key[e] >= T1;
      const unsigned long long mk = __ballot(sel);
      if (sel) {
        const unsigned pos = base + (unsigned)__popcll(mk & lt);
        if (pos < WCAP)
          s_cand[w][pos] =
              make_uint2(key[e], (unsigned)((e >> 2) * 1024 + tid * 4 + (e & 3)));
      }
      base += (unsigned)__popcll(mk);
    }
    if (__builtin_expect(base > WCAP, 0)) {
      // parachute (rare): exact 16th-largest of the wave's 1024 elements,
      // re-pad and re-compact (count = 16 + ties, fits the slab).
      unsigned p2 = 0, need2 = KSEL;
      for (int bit = 31; bit >= 0; --bit) {
        const unsigned want = (p2 << 1) | 1u;
        unsigned cnt = 0;
#pragma unroll
        for (int e = 0; e < 16; ++e)
          cnt += (unsigned)__popcll(__ballot((key[e] >> bit) == want));
        const bool take = cnt >= need2;
        p2 = want - (take ? 0u : 1u);
        need2 = take ? need2 : need2 - cnt;
      }
      if (lane < WCAP) s_cand[w][lane] = make_uint2(0u, 0xFFFFFFFFu);
      base = 0;
#pragma unroll
      for (int e = 0; e < 16; ++e) {
        const bool sel = key[e] >= p2;
        const unsigned long long mk = __ballot(sel);
        if (sel) {
          const unsigned pos = base + (unsigned)__popcll(mk & lt);
          if (pos < WCAP)
            s_cand[w][pos] =
                make_uint2(key[e], (unsigned)((e >> 2) * 1024 + tid * 4 + (e & 3)));
        }
        base += (unsigned)__popcll(mk);
      }
    }
    __syncthreads();  // B1: slabs published

    // ---- final: rank 128 padded candidates, fully unrolled broadcasts ----
    if (tid < 128) {
      const uint2 me = s_cand[tid >> 5][tid & 31];
      unsigned rank = 0, vmk = 0;
#pragma unroll
      for (int u = 0; u < 4; ++u) {
#pragma unroll
        for (int s2 = 0; s2 < WCAP; ++s2) {
          const uint2 o = s_cand[u][s2];  // broadcast read (all lanes same addr)
          rank += (o.x > me.x) || (o.x == me.x && o.y < me.y);
          vmk = umax2(vmk, o.x);
        }
      }
      if (rank < KSEL)  // exactly 16 winners; vmk == row max (it is a cand)
        s_wj[rank] =
            make_uint2(__float_as_uint(__expf(key2f(me.x) - key2f(vmk))), me.y);
    }
    __syncthreads();  // B2: weights published

    // ---- gather: thread = channel; deferred softmax normalization ----
    float ssum = 0.f, a = 0.f;
    if (FT) {
      const float* fb = feat + (size_t)b * N_PIX * N_CH + tid;  // [B,N,C]
#pragma unroll
      for (int k2 = 0; k2 < KSEL; ++k2) {
        const uint2 t = s_wj[k2];
        const float ew = __uint_as_float(t.x);
        ssum += ew;
        a = fmaf(ew, fb[(size_t)t.y * N_CH], a);
      }
    } else {
      const float* fb = feat + ((size_t)(b * N_CH + tid)) * N_PIX;  // [B,C,N]
#pragma unroll
      for (int k2 = 0; k2 < KSEL; ++k2) {
        const uint2 t = s_wj[k2];
        const float ew = __uint_as_float(t.x);
        ssum += ew;
        a = fmaf(ew, fb[t.y], a);
      }
    }
    accs[r] = a / ssum;
    // slab/s_wj reuse next row is safe: all rank reads of row r precede B2(r),
    // all row r+1 writes follow the writer's B2(r) (slabs) / B1(r+1) (s_wj).
  }

  // out[b, c, i0..i0+3] as one float4 per channel (full-line write-combining)
  float4 o;
  o.x = accs[0]; o.y = accs[1]; o.z = accs[2]; o.w = accs[3];
  *(float4*)(out + ((size_t)(b * N_CH + tid)) * N_PIX + i0) = o;
}

extern "C" void kernel_launch(void* const* d_in, const int* in_sizes, int n_in,
                              void* d_out, int out_size, void* d_ws, size_t ws_size,
                              hipStream_t stream) {
  const float* aff = (const float*)d_in[0];
  const float* feat = (const float*)d_in[1];
  float* out = (float*)d_out;
  const size_t feat_t_bytes = (size_t)2 * N_PIX * N_CH * sizeof(float);
  if (ws_size >= feat_t_bytes) {
    float* feat_t = (float*)d_ws;
    dim3 tb(32, 8, 1);
    dim3 tg(N_PIX / 32, N_CH / 32, 2);
    transpose_feat_kernel<<<tg, tb, 0, stream>>>(feat, feat_t);
    topk_rank2_kernel<true><<<2048, 256, 0, stream>>>(aff, feat_t, out);
  } else {
    topk_rank2_kernel<false><<<2048, 256, 0, stream>>>(aff, feat, out);
  }
}

// Round 9
// 66.019 us; speedup vs baseline: 11.9438x; 11.9438x over previous
//
#include <hip/hip_runtime.h>

#define N_PIX 4096
#define N_CH 256
#define KSEL 16
#define PCAP 4    // private per-lane candidate slots (P(overflow) ~ 4e-6/lane)
#define SCAP 128  // compact slab capacity per wave (2 per lane in stage 2)

__device__ __forceinline__ unsigned f2key(float f) {
  unsigned u = __float_as_uint(f);
  return u ^ ((unsigned)((int)u >> 31) | 0x80000000u);
}
__device__ __forceinline__ float key2f(unsigned k) {
  unsigned u = (k & 0x80000000u) ? (k ^ 0x80000000u) : ~k;
  return __uint_as_float(u);
}

// feat [B, C, N] -> feat_t [B, N, C], 32x32 LDS tile transpose
__global__ void transpose_feat_kernel(const float* __restrict__ feat,
                                      float* __restrict__ feat_t) {
  __shared__ float tile[32][33];
  const int b = blockIdx.z;
  const int n0 = blockIdx.x * 32;
  const int c0 = blockIdx.y * 32;
  const int tx = threadIdx.x, ty = threadIdx.y;
  const float* src = feat + (size_t)b * N_CH * N_PIX;
  float* dst = feat_t + (size_t)b * N_PIX * N_CH;
#pragma unroll
  for (int j = 0; j < 32; j += 8)
    tile[ty + j][tx] = src[(size_t)(c0 + ty + j) * N_PIX + n0 + tx];
  __syncthreads();
#pragma unroll
  for (int j = 0; j < 32; j += 8)
    dst[(size_t)(n0 + ty + j) * N_CH + c0 + tx] = tile[tx][ty + j];
}

// Block = 4 waves, ONE ROW PER WAVE, zero barriers until output staging.
//   pass 1: stream row, per-lane float max only (key order == float order).
//   T1    : exact 16th-largest of the TRUNCATED (hi16) lane maxima, 16-step
//           branchless ballot radix. Guarantees: >=16 elements >= T1<<16 and
//           every top_k winner >= T1<<16 (superset; ~16-22 candidates).
//   pass 2: re-stream row (L2-hot), collect candidates into PRIVATE per-lane
//           LDS slots (no per-element ballots), compact via 3-ballot prefix.
//   stage2: exact tie-correct top-16 over <=128 padded candidates (2/lane,
//           early-exit ballot radix; proven in R5). Softmax vs key2f(T2).
// Rare paths: private overflow -> ballot-compact; slab overflow -> streaming
// exact radix. Both measure-zero on continuous data, exact always.
template <bool FT>
__global__ __launch_bounds__(256) void topk_hyb_kernel(
    const float* __restrict__ aff, const float* __restrict__ feat,
    float* __restrict__ out) {
  __shared__ uint2 s_priv[4][64][PCAP];  // 8 KB
  __shared__ uint2 s_slab[4][SCAP];      // 4 KB
  __shared__ uint2 s_wj[4][KSEL];        // 512 B  (exp bits, idx)
  __shared__ float s_out[4][N_CH];       // 4 KB

  const int tid = threadIdx.x;
  const int lane = tid & 63;
  const int w = tid >> 6;
  // chunked bijective XCD swizzle: consecutive rg share an XCD so the blocks
  // writing each 64B output line write-combine in one L2 (R6: WRITE 8.2 MB).
  const int bid = blockIdx.x;
  const int rg = (bid & 7) * 256 + (bid >> 3);
  const int b = rg >> 10;
  const int i0 = (rg & 1023) * 4;
  const int row = rg * 4 + w;
  const unsigned long long lt = (1ull << lane) - 1ull;

  const float4* arow = (const float4*)(aff + (size_t)row * N_PIX);

  // ---- pass 1: per-lane float max (64 values, fmax tree; one f2key at end) ----
  float fm = -3.402823466e+38f;
#pragma unroll
  for (int q = 0; q < 16; ++q) {
    float4 v = arow[q * 64 + lane];
    fm = fmaxf(fm, fmaxf(fmaxf(v.x, v.y), fmaxf(v.z, v.w)));
  }
  const unsigned t = f2key(fm) >> 16;

  // ---- T1: exact 16th-largest truncated lane-max (16-step branchless radix) ----
  unsigned p1 = 0, need1 = KSEL;
#pragma unroll
  for (int bit = 15; bit >= 0; --bit) {
    const unsigned want = (p1 << 1) | 1u;
    const unsigned cnt = (unsigned)__popcll(__ballot((t >> bit) == want));
    const bool take = cnt >= need1;
    p1 = want - (take ? 0u : 1u);
    need1 = take ? need1 : need1 - cnt;
  }
  const float fT = key2f(p1 << 16);  // float threshold (order-equivalent)

  // forbid fusing pass 2 loads with pass 1 (would make 64 keys live -> spill)
  asm volatile("" ::: "memory");

  // ---- pass 2: re-stream (L2-hot), private-collect candidates f >= fT ----
  unsigned cl = 0;
#pragma unroll
  for (int q = 0; q < 16; ++q) {
    float4 v = arow[q * 64 + lane];
    const float fv[4] = {v.x, v.y, v.z, v.w};
#pragma unroll
    for (int c = 0; c < 4; ++c) {
      if (fv[c] >= fT) {
        if (cl < PCAP)
          s_priv[w][lane][cl] =
              make_uint2(f2key(fv[c]), (unsigned)(q * 256 + lane * 4 + c));
        ++cl;
      }
    }
  }

  // pad slab (overwritten below; same-wave ds ops are in program order)
  s_slab[w][lane] = make_uint2(0u, 0xFFFFFFFFu);
  s_slab[w][lane + 64] = make_uint2(0u, 0xFFFFFFFFu);

  unsigned total;
  const bool over = (__ballot(cl > PCAP) != 0ull);
  if (__builtin_expect(!over, 1)) {
    // 3-ballot prefix sum of cl (0..4) -> compact positions, no atomics
    const unsigned long long b0 = __ballot(cl & 1u);
    const unsigned long long b1 = __ballot((cl >> 1) & 1u);
    const unsigned long long b2 = __ballot((cl >> 2) & 1u);
    const unsigned start = (unsigned)__popcll(b0 & lt) +
                           2u * (unsigned)__popcll(b1 & lt) +
                           4u * (unsigned)__popcll(b2 & lt);
    total = (unsigned)__popcll(b0) + 2u * (unsigned)__popcll(b1) +
            4u * (unsigned)__popcll(b2);
    for (unsigned c = 0; c < cl; ++c)
      if (start + c < SCAP) s_slab[w][start + c] = s_priv[w][lane][c];
  } else {
    // rare: per-element ballot-rank compaction (third stream, L2-hot)
    unsigned base = 0;
    for (int q = 0; q < 16; ++q) {
      float4 v = arow[q * 64 + lane];
      const float fv[4] = {v.x, v.y, v.z, v.w};
      for (int c = 0; c < 4; ++c) {
        const bool sel = fv[c] >= fT;
        const unsigned long long mk = __ballot(sel);
        if (sel) {
          const unsigned pos = base + (unsigned)__popcll(mk & lt);
          if (pos < SCAP)
            s_slab[w][pos] =
                make_uint2(f2key(fv[c]), (unsigned)(q * 256 + lane * 4 + c));
        }
        base += (unsigned)__popcll(mk);
      }
    }
    total = base;
  }

  if (__builtin_expect(total <= SCAP, 1)) {
    // ---- stage 2: exact top-16 among <=128 padded candidates (2/lane) ----
    const uint2 c0 = s_slab[w][lane];
    const uint2 c1 = s_slab[w][lane + 64];
    unsigned p2 = 0, need2 = KSEL;
    bool early = false;
    int bit = 31;
    for (; bit >= 0; --bit) {
      const unsigned want = (p2 << 1) | 1u;
      // pads (key 0) never match: want is odd-prefixed and real keys > 0
      const unsigned cnt = (unsigned)__popcll(__ballot((c0.x >> bit) == want)) +
                           (unsigned)__popcll(__ballot((c1.x >> bit) == want));
      if (cnt >= need2) {
        p2 = want;
        if (cnt == need2) { early = true; break; }
      } else {
        need2 -= cnt;
        p2 <<= 1;
      }
    }
    bool w0, w1;
    float vref;
    if (early) {
      const unsigned thr2 = p2 << bit;  // exactly KSEL keys >= thr2, no ties
      w0 = c0.x >= thr2;
      w1 = c1.x >= thr2;
      vref = key2f(thr2);
    } else {
      w0 = c0.x > p2;
      w1 = c1.x > p2;
      vref = key2f(p2);
      bool t0 = (c0.x == p2) && (c0.y != 0xFFFFFFFFu);
      bool t1 = (c1.x == p2) && (c1.y != 0xFFFFFFFFu);
      for (unsigned q = 0; q < need2; ++q) {  // lowest-index ties (top_k order)
        unsigned mi0 = t0 ? c0.y : 0xFFFFFFFFu;
        unsigned mi1 = t1 ? c1.y : 0xFFFFFFFFu;
        unsigned mi = mi0 < mi1 ? mi0 : mi1;
#pragma unroll
        for (int off = 32; off; off >>= 1) {
          unsigned o = (unsigned)__shfl_xor((int)mi, off, 64);
          mi = o < mi ? o : mi;
        }
        if (t0 && c0.y == mi) { w0 = true; t0 = false; }
        else if (t1 && c1.y == mi) { w1 = true; t1 = false; }
      }
    }
    const unsigned long long m0 = __ballot(w0);
    const unsigned long long m1 = __ballot(w1);
    const unsigned n0w = (unsigned)__popcll(m0);
    if (w0)
      s_wj[w][(unsigned)__popcll(m0 & lt)] =
          make_uint2(__float_as_uint(__expf(key2f(c0.x) - vref)), c0.y);
    if (w1)
      s_wj[w][n0w + (unsigned)__popcll(m1 & lt)] =
          make_uint2(__float_as_uint(__expf(key2f(c1.x) - vref)), c1.y);
  } else {
    // ---- ultra-cold exact path (adversarial data only): streaming radix ----
    unsigned p2 = 0, need2 = KSEL;
    for (int bit = 31; bit >= 0; --bit) {
      const unsigned want = (p2 << 1) | 1u;
      unsigned cnt = 0;
      for (int q = 0; q < 16; ++q) {
        float4 v = arow[q * 64 + lane];
        cnt += (unsigned)__popcll(__ballot((f2key(v.x) >> bit) == want));
        cnt += (unsigned)__popcll(__ballot((f2key(v.y) >> bit) == want));
        cnt += (unsigned)__popcll(__ballot((f2key(v.z) >> bit) == want));
        cnt += (unsigned)__popcll(__ballot((f2key(v.w) >> bit) == want));
      }
      const bool take = cnt >= need2;
      p2 = want - (take ? 0u : 1u);
      need2 = take ? need2 : need2 - cnt;
    }
    const float vref = key2f(p2);
    unsigned rk = 0;
    for (int q = 0; q < 16; ++q) {
      float4 v = arow[q * 64 + lane];
      const float fv[4] = {v.x, v.y, v.z, v.w};
      for (int c = 0; c < 4; ++c) {
        const unsigned kk = f2key(fv[c]);
        const bool sel = kk > p2;
        const unsigned long long mk = __ballot(sel);
        if (sel) {
          const unsigned pos = rk + (unsigned)__popcll(mk & lt);
          if (pos < KSEL)
            s_wj[w][pos] = make_uint2(__float_as_uint(__expf(fv[c] - vref)),
                                      (unsigned)(q * 256 + lane * 4 + c));
        }
        rk += (unsigned)__popcll(mk);
      }
    }
    unsigned jprev = 0xFFFFFFFFu;
    for (unsigned tq = rk; tq < KSEL; ++tq) {  // lowest-index ties, ascending
      unsigned mi = 0xFFFFFFFFu;
      for (int q = 0; q < 16; ++q) {
        float4 v = arow[q * 64 + lane];
        const float fv[4] = {v.x, v.y, v.z, v.w};
        for (int c = 0; c < 4; ++c) {
          const unsigned j = (unsigned)(q * 256 + lane * 4 + c);
          if (f2key(fv[c]) == p2 && (jprev == 0xFFFFFFFFu || j > jprev) && j < mi)
            mi = j;
        }
      }
#pragma unroll
      for (int off = 32; off; off >>= 1) {
        unsigned o = (unsigned)__shfl_xor((int)mi, off, 64);
        mi = o < mi ? o : mi;
      }
      if (lane == 0) s_wj[w][tq] = make_uint2(__float_as_uint(1.0f), mi);
      jprev = mi;
    }
  }

  // ---- epilogue (same-wave LDS RAW, no barrier): softmax denom + gather ----
  float ssum = 0.f;
#pragma unroll
  for (int k = 0; k < KSEL; ++k) ssum += __uint_as_float(s_wj[w][k].x);
  const float inv = 1.0f / ssum;

  float ax = 0.f, ay = 0.f, az = 0.f, aw2 = 0.f;
  if (FT) {
    const float* fb = feat + (size_t)b * N_PIX * N_CH + lane * 4;  // [B,N,C]
#pragma unroll
    for (int k = 0; k < KSEL; ++k) {
      const uint2 tt = s_wj[w][k];  // broadcast read
      const float ew = __uint_as_float(tt.x);
      const float4 f = *(const float4*)(fb + (size_t)tt.y * N_CH);
      ax += ew * f.x; ay += ew * f.y; az += ew * f.z; aw2 += ew * f.w;
    }
  } else {
    const float* fb = feat + (size_t)b * N_CH * N_PIX;  // [B,C,N] fallback
    const int c0s = lane * 4;
#pragma unroll
    for (int k = 0; k < KSEL; ++k) {
      const uint2 tt = s_wj[w][k];
      const float ew = __uint_as_float(tt.x);
      ax += ew * fb[(size_t)(c0s + 0) * N_PIX + tt.y];
      ay += ew * fb[(size_t)(c0s + 1) * N_PIX + tt.y];
      az += ew * fb[(size_t)(c0s + 2) * N_PIX + tt.y];
      aw2 += ew * fb[(size_t)(c0s + 3) * N_PIX + tt.y];
    }
  }
  float4 accv;
  accv.x = ax * inv; accv.y = ay * inv; accv.z = az * inv; accv.w = aw2 * inv;
  *(float4*)&s_out[w][lane * 4] = accv;

  __syncthreads();  // the only block barrier: full-line output assembly

  {
    const int c = tid;
    float4 o;
    o.x = s_out[0][c]; o.y = s_out[1][c]; o.z = s_out[2][c]; o.w = s_out[3][c];
    *(float4*)(out + ((size_t)(b * N_CH + c)) * N_PIX + i0) = o;
  }
}

extern "C" void kernel_launch(void* const* d_in, const int* in_sizes, int n_in,
                              void* d_out, int out_size, void* d_ws, size_t ws_size,
                              hipStream_t stream) {
  const float* aff = (const float*)d_in[0];
  const float* feat = (const float*)d_in[1];
  float* out = (float*)d_out;
  const size_t feat_t_bytes = (size_t)2 * N_PIX * N_CH * sizeof(float);
  if (ws_size >= feat_t_bytes) {
    float* feat_t = (float*)d_ws;
    dim3 tb(32, 8, 1);
    dim3 tg(N_PIX / 32, N_CH / 32, 2);
    transpose_feat_kernel<<<tg, tb, 0, stream>>>(feat, feat_t);
    topk_hyb_kernel<true><<<2048, 256, 0, stream>>>(aff, feat_t, out);
  } else {
    topk_hyb_kernel<false><<<2048, 256, 0, stream>>>(aff, feat, out);
  }
}

// Round 10
// 51.812 us; speedup vs baseline: 15.2188x; 1.2742x over previous
//
#include <hip/hip_runtime.h>

#define N_PIX 4096
#define N_CH 256
#define KSEL 16
#define SCAP 64

__device__ __forceinline__ unsigned f2key(float f) {
  unsigned u = __float_as_uint(f);
  return u ^ ((unsigned)((int)u >> 31) | 0x80000000u);
}
__device__ __forceinline__ float key2f(unsigned k) {
  unsigned u = (k & 0x80000000u) ? (k ^ 0x80000000u) : ~k;
  return __uint_as_float(u);
}
__device__ __forceinline__ unsigned umax2(unsigned a, unsigned b) { return a > b ? a : b; }

// feat [B, C, N] -> feat_t [B, N, C], 32x32 LDS tile transpose
__global__ void transpose_feat_kernel(const float* __restrict__ feat,
                                      float* __restrict__ feat_t) {
  __shared__ float tile[32][33];
  const int b = blockIdx.z;
  const int n0 = blockIdx.x * 32;
  const int c0 = blockIdx.y * 32;
  const int tx = threadIdx.x, ty = threadIdx.y;
  const float* src = feat + (size_t)b * N_CH * N_PIX;
  float* dst = feat_t + (size_t)b * N_PIX * N_CH;
#pragma unroll
  for (int j = 0; j < 32; j += 8)
    tile[ty + j][tx] = src[(size_t)(c0 + ty + j) * N_PIX + n0 + tx];
  __syncthreads();
#pragma unroll
  for (int j = 0; j < 32; j += 8)
    dst[(size_t)(n0 + ty + j) * N_CH + c0 + tx] = tile[tx][ty + j];
}

// Block = 4 waves, ONE ROW PER WAVE, SINGLE global pass, zero barriers until
// output staging. The whole row lives in registers as uint4 kv[16] (64 keys).
// __launch_bounds__(256,2) lifts the VGPR cap so the allocator does NOT spill
// (R5 failure mode: cap-52 -> 16KB/wave scratch). Selection:
//   T1 : exact 16th-largest of the hi-16-truncated lane maxima (16-step
//        branchless ballot radix). >=16 row elements >= thrK=T1<<16, and every
//        top-16 element >= thrK (16 lanes each hold an element >= thrK).
//   extract candidates >= thrK from REGISTERS via ballot-rank (64 unrolled
//        steps, VALU/SALU only) into a padded per-wave LDS slab (~20 cands).
//   stage2: exact tie-correct top-16 over <=64 padded candidates (1/lane,
//        early-exit ballot radix + lowest-index tie path; R5/R9-proven).
// Softmax deferred: ew = exp(v - key2f(T2ish)), normalize in epilogue.
template <bool FT>
__global__ __launch_bounds__(256, 2) void topk_reg_kernel(
    const float* __restrict__ aff, const float* __restrict__ feat,
    float* __restrict__ out) {
  __shared__ uint2 s_slab[4][SCAP];  // (key, idx) padded
  __shared__ uint2 s_wj[4][KSEL];    // (exp bits, idx)
  __shared__ float s_out[4][N_CH];

  const int tid = threadIdx.x;
  const int lane = tid & 63;
  const int w = tid >> 6;
  // bijective chunked XCD swizzle (2048 = 8*256): consecutive rg share an XCD
  // so the blocks writing each 64B output line write-combine in one L2.
  const int bid = blockIdx.x;
  const int rg = (bid & 7) * 256 + (bid >> 3);
  const int b = rg >> 10;
  const int i0 = (rg & 1023) * 4;
  const int row = rg * 4 + w;
  const unsigned long long lt = (1ull << lane) - 1ull;

  // ---- single pass: whole row into registers (vector uint4, const-indexed) ----
  const float4* arow = (const float4*)(aff + (size_t)row * N_PIX);
  uint4 kv[16];
  unsigned m = 0;
#pragma unroll
  for (int q = 0; q < 16; ++q) {
    const float4 v = arow[q * 64 + lane];
    const unsigned k0 = f2key(v.x), k1 = f2key(v.y), k2 = f2key(v.z), k3 = f2key(v.w);
    kv[q].x = k0; kv[q].y = k1; kv[q].z = k2; kv[q].w = k3;
    m = umax2(m, umax2(umax2(k0, k1), umax2(k2, k3)));
  }

  // ---- T1: exact 16th-largest truncated lane-max (16-step branchless radix) ----
  const unsigned t = m >> 16;
  unsigned p1 = 0, need1 = KSEL;
#pragma unroll
  for (int bit = 15; bit >= 0; --bit) {
    const unsigned want = (p1 << 1) | 1u;
    const unsigned cnt = (unsigned)__popcll(__ballot((t >> bit) == want));
    const bool take = cnt >= need1;
    p1 = want - (take ? 0u : 1u);
    need1 = take ? need1 : need1 - cnt;
  }
  const unsigned thrK = p1 << 16;

  // pad slab (same-wave program order; no barrier needed)
  s_slab[w][lane] = make_uint2(0u, 0xFFFFFFFFu);

  // ---- extract candidates >= thrK from registers (ballot-rank, no atomics) ----
  unsigned base = 0;
#pragma unroll
  for (int q = 0; q < 16; ++q) {
    const unsigned kk[4] = {kv[q].x, kv[q].y, kv[q].z, kv[q].w};
#pragma unroll
    for (int c = 0; c < 4; ++c) {
      const bool sel = kk[c] >= thrK;
      const unsigned long long mk = __ballot(sel);
      if (sel) {
        const unsigned pos = base + (unsigned)__popcll(mk & lt);
        if (pos < SCAP)
          s_slab[w][pos] = make_uint2(kk[c], (unsigned)(q * 256 + lane * 4 + c));
      }
      base += (unsigned)__popcll(mk);
    }
  }

  if (__builtin_expect(base > SCAP, 0)) {
    // parachute (measure-zero): exact 16th-largest of all 4096 via full-width
    // radix over the register array, then re-extract (<= 16+ties <= slab).
    unsigned p2 = 0, need2 = KSEL;
    for (int bit = 31; bit >= 0; --bit) {
      const unsigned want = (p2 << 1) | 1u;
      unsigned cnt = 0;
#pragma unroll
      for (int q = 0; q < 16; ++q) {
        cnt += (unsigned)__popcll(__ballot((kv[q].x >> bit) == want));
        cnt += (unsigned)__popcll(__ballot((kv[q].y >> bit) == want));
        cnt += (unsigned)__popcll(__ballot((kv[q].z >> bit) == want));
        cnt += (unsigned)__popcll(__ballot((kv[q].w >> bit) == want));
      }
      const bool take = cnt >= need2;
      p2 = want - (take ? 0u : 1u);
      need2 = take ? need2 : need2 - cnt;
    }
    s_slab[w][lane] = make_uint2(0u, 0xFFFFFFFFu);
    base = 0;
#pragma unroll
    for (int q = 0; q < 16; ++q) {
      const unsigned kk[4] = {kv[q].x, kv[q].y, kv[q].z, kv[q].w};
#pragma unroll
      for (int c = 0; c < 4; ++c) {
        const bool sel = kk[c] >= p2;
        const unsigned long long mk = __ballot(sel);
        if (sel) {
          const unsigned pos = base + (unsigned)__popcll(mk & lt);
          if (pos < SCAP)
            s_slab[w][pos] = make_uint2(kk[c], (unsigned)(q * 256 + lane * 4 + c));
        }
        base += (unsigned)__popcll(mk);
      }
    }
  }

  // ---- stage 2: exact top-16 among <=64 padded candidates (1 per lane) ----
  {
    const uint2 cc = s_slab[w][lane];  // same-wave RAW (lgkmcnt only)
    const unsigned cv = cc.x;
    const unsigned cj = cc.y;
    unsigned p2 = 0, need2 = KSEL;
    bool early = false;
    int bit = 31;
    for (; bit >= 0; --bit) {
      const unsigned want = (p2 << 1) | 1u;
      // pads (key 0) never match an odd-prefixed want
      const unsigned cnt = (unsigned)__popcll(__ballot((cv >> bit) == want));
      if (cnt >= need2) {
        p2 = want;
        if (cnt == need2) { early = true; break; }
      } else {
        need2 -= cnt;
        p2 <<= 1;
      }
    }
    bool win;
    float vref;
    if (early) {
      const unsigned thr2 = p2 << bit;  // exactly KSEL candidates >= thr2
      win = cv >= thr2;
      vref = key2f(thr2);
    } else {
      win = cv > p2;
      vref = key2f(p2);
      bool tq = (cv == p2) && (cj != 0xFFFFFFFFu);
      for (unsigned q = 0; q < need2; ++q) {  // lowest-index ties (top_k order)
        unsigned mi = tq ? cj : 0xFFFFFFFFu;
#pragma unroll
        for (int off = 32; off; off >>= 1) {
          const unsigned o = (unsigned)__shfl_xor((int)mi, off, 64);
          mi = o < mi ? o : mi;
        }
        if (tq && cj == mi) { win = true; tq = false; }
      }
    }
    const unsigned long long wm = __ballot(win);
    if (win) {
      const unsigned rk = (unsigned)__popcll(wm & lt);
      s_wj[w][rk] = make_uint2(__float_as_uint(__expf(key2f(cv) - vref)), cj);
    }
  }

  // ---- epilogue (same-wave LDS RAW): softmax denom + gather, lane = 4 chans ----
  float ssum = 0.f;
#pragma unroll
  for (int k = 0; k < KSEL; ++k) ssum += __uint_as_float(s_wj[w][k].x);
  const float inv = 1.0f / ssum;

  float ax = 0.f, ay = 0.f, az = 0.f, aw2 = 0.f;
  if (FT) {
    const float* fb = feat + (size_t)b * N_PIX * N_CH + lane * 4;  // [B,N,C]
#pragma unroll
    for (int k = 0; k < KSEL; ++k) {
      const uint2 tt = s_wj[w][k];  // broadcast read
      const float ew = __uint_as_float(tt.x);
      const float4 f = *(const float4*)(fb + (size_t)tt.y * N_CH);
      ax += ew * f.x; ay += ew * f.y; az += ew * f.z; aw2 += ew * f.w;
    }
  } else {
    const float* fb = feat + (size_t)b * N_CH * N_PIX;  // [B,C,N] fallback
    const int c0s = lane * 4;
#pragma unroll
    for (int k = 0; k < KSEL; ++k) {
      const uint2 tt = s_wj[w][k];
      const float ew = __uint_as_float(tt.x);
      ax += ew * fb[(size_t)(c0s + 0) * N_PIX + tt.y];
      ay += ew * fb[(size_t)(c0s + 1) * N_PIX + tt.y];
      az += ew * fb[(size_t)(c0s + 2) * N_PIX + tt.y];
      aw2 += ew * fb[(size_t)(c0s + 3) * N_PIX + tt.y];
    }
  }
  float4 accv;
  accv.x = ax * inv; accv.y = ay * inv; accv.z = az * inv; accv.w = aw2 * inv;
  *(float4*)&s_out[w][lane * 4] = accv;

  __syncthreads();  // the only block barrier: full-line output assembly

  {
    const int c = tid;
    float4 o;
    o.x = s_out[0][c]; o.y = s_out[1][c]; o.z = s_out[2][c]; o.w = s_out[3][c];
    *(float4*)(out + ((size_t)(b * N_CH + c)) * N_PIX + i0) = o;
  }
}

extern "C" void kernel_launch(void* const* d_in, const int* in_sizes, int n_in,
                              void* d_out, int out_size, void* d_ws, size_t ws_size,
                              hipStream_t stream) {
  const float* aff = (const float*)d_in[0];
  const float* feat = (const float*)d_in[1];
  float* out = (float*)d_out;
  const size_t feat_t_bytes = (size_t)2 * N_PIX * N_CH * sizeof(float);
  if (ws_size >= feat_t_bytes) {
    float* feat_t = (float*)d_ws;
    dim3 tb(32, 8, 1);
    dim3 tg(N_PIX / 32, N_CH / 32, 2);
    transpose_feat_kernel<<<tg, tb, 0, stream>>>(feat, feat_t);
    topk_reg_kernel<true><<<2048, 256, 0, stream>>>(aff, feat_t, out);
  } else {
    topk_reg_kernel<false><<<2048, 256, 0, stream>>>(aff, feat, out);
  }
}